// Round 1
// baseline (92.029 us; speedup 1.0000x reference)
//
#include <hip/hip_runtime.h>

// AffinityLoss: logits (2,19,384,384) fp32, labels (2,384,384) int32 -> scalar fp32.
// Reformulated from (base,a,b) triples to (pixel, offset) pairs with integer
// multiplicities: 23.6M loss terms -> 3.8M f-evals. fp64 accumulation.

#define IGNORE_INDEX (-100)

constexpr int Hh = 384, Ww = 384, Cc = 19;
constexpr int HP = 382, WP = 382;            // h-k+1, w-k+1
constexpr int TX = 32, TY = 8;               // pixel tile per block (256 thr)
constexpr int LXX = TX + 4;                  // halo: dx in [-2,2]
constexpr int LYY = TY + 2;                  // halo: dy in [0,2]

// multiplicity of (pixel row y, row-offset di>=0): #ai in [0,3) with
// ai+di<=2 and base row y-ai in [0,HP)
__device__ __forceinline__ int mult_y(int y, int di) {
    int lo = y - (HP - 1); if (lo < 0) lo = 0;
    int hi = 2 - di;       if (y < hi) hi = y;
    int c = hi - lo + 1;   return c > 0 ? c : 0;
}
// multiplicity of (pixel col x, col-offset dj in [-2,2])
__device__ __forceinline__ int mult_x(int x, int dj) {
    int lo = (-dj > 0) ? -dj : 0;
    int lo2 = x - (WP - 1); if (lo2 > lo) lo = lo2;
    int hi = (2 - dj < 2) ? (2 - dj) : 2;
    if (x < hi) hi = x;
    int c = hi - lo + 1;   return c > 0 ? c : 0;
}

__device__ __forceinline__ float bce_term(float x, float y) {
    // max(x,0) - x*y + log1p(exp(-|x|))
    return fmaxf(x, 0.0f) - x * y + log1pf(expf(-fabsf(x)));
}

__global__ __launch_bounds__(256) void aff_loss_kernel(
        const float* __restrict__ logits, const int* __restrict__ labels,
        double* __restrict__ acc) {
    __shared__ float  sv[LYY * LXX * Cc];   // [row][col][chan], stride 19 (odd)
    __shared__ int    sl[LYY * LXX];
    __shared__ double sred[4];

    const int n   = blockIdx.z;
    const int tx0 = blockIdx.x * TX;
    const int ty0 = blockIdx.y * TY;
    const int tid = threadIdx.x;

    const float* img = logits + (size_t)n * Cc * Hh * Ww;
    const int*   lab = labels + (size_t)n * Hh * Ww;

    // stage tile + halo (clamped at borders; clamped pixels only ever used
    // with multiplicity 0, clamping just keeps values finite)
    for (int idx = tid; idx < LYY * LXX; idx += 256) {
        int r = idx / LXX, col = idx - r * LXX;
        int gy = ty0 + r;       if (gy > Hh - 1) gy = Hh - 1;
        int gx = tx0 + col - 2; if (gx < 0) gx = 0; if (gx > Ww - 1) gx = Ww - 1;
        sl[idx] = lab[gy * Ww + gx];
        #pragma unroll
        for (int c = 0; c < Cc; ++c)
            sv[idx * Cc + c] = img[(size_t)c * Hh * Ww + gy * Ww + gx];
    }
    __syncthreads();

    const int tx = tid & (TX - 1), ty = tid / TX;
    const int x = tx0 + tx, y = ty0 + ty;
    const int lp_idx = ty * LXX + (tx + 2);

    float v[Cc];
    #pragma unroll
    for (int c = 0; c < Cc; ++c) v[c] = sv[lp_idx * Cc + c];
    const int lp = sl[lp_idx];
    const bool vp = (lp != IGNORE_INDEX);

    double tsum = 0.0;

    // diagonal (a==b): x = |v|^2 >= 0, y = valid
    {
        float xd = 0.0f;
        #pragma unroll
        for (int c = 0; c < Cc; ++c) xd = fmaf(v[c], v[c], xd);
        float f = (vp ? 0.0f : xd) + log1pf(expf(-xd));
        int w = mult_y(y, 0) * mult_x(x, 0);
        tsum += (double)((float)w * f);
    }

    // 12 lexicographically-positive offsets (each counted twice: (a,b),(b,a))
    const int DY[12] = {0, 0, 1, 1, 1, 1, 1, 2, 2, 2, 2, 2};
    const int DX[12] = {1, 2, -2, -1, 0, 1, 2, -2, -1, 0, 1, 2};
    #pragma unroll
    for (int d = 0; d < 12; ++d) {
        const int dy = DY[d], dx = DX[d];
        const int w = mult_y(y, dy) * mult_x(x, dx);
        const int lq_idx = (ty + dy) * LXX + (tx + 2 + dx);
        float xd = 0.0f;
        #pragma unroll
        for (int c = 0; c < Cc; ++c) xd = fmaf(v[c], sv[lq_idx * Cc + c], xd);
        const int lq = sl[lq_idx];
        const float yv = (vp && lq == lp) ? 1.0f : 0.0f;  // lq==lp implies lq valid when lp valid
        float f = bce_term(xd, yv);
        tsum += (double)((float)(2 * w) * f);
    }

    // reduce: wave shuffle -> LDS -> one atomic per block
    for (int off = 32; off > 0; off >>= 1) tsum += __shfl_down(tsum, off, 64);
    const int wid = tid >> 6;
    if ((tid & 63) == 0) sred[wid] = tsum;
    __syncthreads();
    if (tid == 0) {
        double s = sred[0] + sred[1] + sred[2] + sred[3];
        atomicAdd(acc, s);
    }
}

__global__ void finalize_kernel(const double* __restrict__ acc,
                                float* __restrict__ out) {
    // mean over n*9*9*L = 2*81*382*382 = 23,639,688 terms
    out[0] = (float)(acc[0] * (1.0 / 23639688.0));
}

extern "C" void kernel_launch(void* const* d_in, const int* in_sizes, int n_in,
                              void* d_out, int out_size, void* d_ws, size_t ws_size,
                              hipStream_t stream) {
    const float* logits = (const float*)d_in[0];
    const int*   labels = (const int*)d_in[1];
    float* out = (float*)d_out;
    double* acc = (double*)d_ws;

    hipMemsetAsync(d_ws, 0, sizeof(double), stream);

    dim3 grid(Ww / TX, Hh / TY, 2);   // 12 x 48 x 2 = 1152 blocks
    aff_loss_kernel<<<grid, 256, 0, stream>>>(logits, labels, acc);
    finalize_kernel<<<1, 1, 0, stream>>>(acc, out);
}

// Round 2
// 90.888 us; speedup vs baseline: 1.0126x; 1.0126x over previous
//
#include <hip/hip_runtime.h>

// AffinityLoss: logits (2,19,384,384) fp32, labels (2,384,384) int32 -> scalar fp32.
// Reformulated from (base,a,b) triples to (pixel, offset) pairs with integer
// multiplicities: 23.6M loss terms -> 3.8M f-evals.
// R2: per-block partial sums into distinct d_ws slots (no memset dispatch,
// no same-address atomic contention); finalize reduces 1152 doubles.

#define IGNORE_INDEX (-100)

constexpr int Hh = 384, Ww = 384, Cc = 19;
constexpr int HP = 382, WP = 382;            // h-k+1, w-k+1
constexpr int TX = 32, TY = 8;               // pixel tile per block (256 thr)
constexpr int LXX = TX + 4;                  // halo: dx in [-2,2]
constexpr int LYY = TY + 2;                  // halo: dy in [0,2]
constexpr int NBX = Ww / TX, NBY = Hh / TY;  // 12, 48
constexpr int NBLK = NBX * NBY * 2;          // 1152

// multiplicity of (pixel row y, row-offset di>=0): #ai in [0,3) with
// ai+di<=2 and base row y-ai in [0,HP)
__device__ __forceinline__ int mult_y(int y, int di) {
    int lo = y - (HP - 1); if (lo < 0) lo = 0;
    int hi = 2 - di;       if (y < hi) hi = y;
    int c = hi - lo + 1;   return c > 0 ? c : 0;
}
// multiplicity of (pixel col x, col-offset dj in [-2,2])
__device__ __forceinline__ int mult_x(int x, int dj) {
    int lo = (-dj > 0) ? -dj : 0;
    int lo2 = x - (WP - 1); if (lo2 > lo) lo = lo2;
    int hi = (2 - dj < 2) ? (2 - dj) : 2;
    if (x < hi) hi = x;
    int c = hi - lo + 1;   return c > 0 ? c : 0;
}

__device__ __forceinline__ float bce_term(float x, float y) {
    // max(x,0) - x*y + log1p(exp(-|x|))
    return fmaxf(x, 0.0f) - x * y + log1pf(expf(-fabsf(x)));
}

__global__ __launch_bounds__(256) void aff_loss_kernel(
        const float* __restrict__ logits, const int* __restrict__ labels,
        double* __restrict__ partial) {
    __shared__ float  sv[LYY * LXX * Cc];   // [row][col][chan], stride 19 (odd)
    __shared__ int    sl[LYY * LXX];
    __shared__ double sred[4];

    const int n   = blockIdx.z;
    const int tx0 = blockIdx.x * TX;
    const int ty0 = blockIdx.y * TY;
    const int tid = threadIdx.x;
    const int bid = (blockIdx.z * NBY + blockIdx.y) * NBX + blockIdx.x;

    const float* img = logits + (size_t)n * Cc * Hh * Ww;
    const int*   lab = labels + (size_t)n * Hh * Ww;

    // stage tile + halo (clamped at borders; clamped pixels only ever used
    // with multiplicity 0, clamping just keeps values finite)
    for (int idx = tid; idx < LYY * LXX; idx += 256) {
        int r = idx / LXX, col = idx - r * LXX;
        int gy = ty0 + r;       if (gy > Hh - 1) gy = Hh - 1;
        int gx = tx0 + col - 2; if (gx < 0) gx = 0; if (gx > Ww - 1) gx = Ww - 1;
        sl[idx] = lab[gy * Ww + gx];
        #pragma unroll
        for (int c = 0; c < Cc; ++c)
            sv[idx * Cc + c] = img[(size_t)c * Hh * Ww + gy * Ww + gx];
    }
    __syncthreads();

    const int tx = tid & (TX - 1), ty = tid / TX;
    const int x = tx0 + tx, y = ty0 + ty;
    const int lp_idx = ty * LXX + (tx + 2);

    float v[Cc];
    #pragma unroll
    for (int c = 0; c < Cc; ++c) v[c] = sv[lp_idx * Cc + c];
    const int lp = sl[lp_idx];
    const bool vp = (lp != IGNORE_INDEX);

    double tsum = 0.0;

    // diagonal (a==b): x = |v|^2 >= 0, y = valid
    {
        float xd = 0.0f;
        #pragma unroll
        for (int c = 0; c < Cc; ++c) xd = fmaf(v[c], v[c], xd);
        float f = (vp ? 0.0f : xd) + log1pf(expf(-xd));
        int w = mult_y(y, 0) * mult_x(x, 0);
        tsum += (double)((float)w * f);
    }

    // 12 lexicographically-positive offsets (each counted twice: (a,b),(b,a))
    const int DY[12] = {0, 0, 1, 1, 1, 1, 1, 2, 2, 2, 2, 2};
    const int DX[12] = {1, 2, -2, -1, 0, 1, 2, -2, -1, 0, 1, 2};
    #pragma unroll
    for (int d = 0; d < 12; ++d) {
        const int dy = DY[d], dx = DX[d];
        const int w = mult_y(y, dy) * mult_x(x, dx);
        const int lq_idx = (ty + dy) * LXX + (tx + 2 + dx);
        float xd = 0.0f;
        #pragma unroll
        for (int c = 0; c < Cc; ++c) xd = fmaf(v[c], sv[lq_idx * Cc + c], xd);
        const int lq = sl[lq_idx];
        const float yv = (vp && lq == lp) ? 1.0f : 0.0f;
        float f = bce_term(xd, yv);
        tsum += (double)((float)(2 * w) * f);
    }

    // reduce: wave shuffle -> LDS -> one plain store per block (distinct slot)
    for (int off = 32; off > 0; off >>= 1) tsum += __shfl_down(tsum, off, 64);
    const int wid = tid >> 6;
    if ((tid & 63) == 0) sred[wid] = tsum;
    __syncthreads();
    if (tid == 0)
        partial[bid] = sred[0] + sred[1] + sred[2] + sred[3];
}

__global__ __launch_bounds__(256) void finalize_kernel(
        const double* __restrict__ partial, float* __restrict__ out) {
    __shared__ double sred[4];
    const int tid = threadIdx.x;
    double s = 0.0;
    for (int i = tid; i < NBLK; i += 256) s += partial[i];
    for (int off = 32; off > 0; off >>= 1) s += __shfl_down(s, off, 64);
    if ((tid & 63) == 0) sred[tid >> 6] = s;
    __syncthreads();
    if (tid == 0) {
        // mean over n*9*9*L = 2*81*382*382 = 23,639,688 terms
        double tot = sred[0] + sred[1] + sred[2] + sred[3];
        out[0] = (float)(tot * (1.0 / 23639688.0));
    }
}

extern "C" void kernel_launch(void* const* d_in, const int* in_sizes, int n_in,
                              void* d_out, int out_size, void* d_ws, size_t ws_size,
                              hipStream_t stream) {
    const float* logits = (const float*)d_in[0];
    const int*   labels = (const int*)d_in[1];
    float* out = (float*)d_out;
    double* partial = (double*)d_ws;   // NBLK doubles, written unconditionally

    dim3 grid(NBX, NBY, 2);   // 12 x 48 x 2 = 1152 blocks
    aff_loss_kernel<<<grid, 256, 0, stream>>>(logits, labels, partial);
    finalize_kernel<<<1, 256, 0, stream>>>(partial, out);
}